// Round 5
// baseline (1167.210 us; speedup 1.0000x reference)
//
#include <hip/hip_runtime.h>
#include <hip/hip_bf16.h>
#include <math.h>

#define MTOK 16384      // B*L tokens
#define DM   768
#define DI   1536
#define DS   16
#define RNK  48
#define LSEQ 2048
#define NBATCH 8
#define EPSV 1e-5f
#define CHK  16         // time chunks for the scan
#define CLEN (LSEQ / CHK)
#define BM 128
#define BN 128
#define BK 32
#define KSPLIT 8        // split-K factor for the x_proj GEMM
#define EPS_STRIDE 72   // epilogue LDS row stride (shorts), 16B-aligned, conflict-light

typedef __hip_bfloat16 bf16;
typedef __attribute__((ext_vector_type(8))) short short8;
typedef __attribute__((ext_vector_type(4))) float floatx4;

__device__ __forceinline__ float b2f(bf16 v){ return __bfloat162float(v); }
__device__ __forceinline__ bf16  f2b(float v){ return __float2bfloat16(v); }
__device__ __forceinline__ float u2f(unsigned short u){
    union { unsigned int i; float f; } v; v.i = ((unsigned int)u) << 16; return v.f;
}
__device__ __forceinline__ unsigned pack_bf2(float a, float b){
    bf16 ta = f2b(a), tb = f2b(b);
    return (unsigned)(*(unsigned short*)&ta) | ((unsigned)(*(unsigned short*)&tb) << 16);
}
__device__ __forceinline__ float silu_f(float x){
    return x * __builtin_amdgcn_rcpf(1.f + __expf(-x));
}
__device__ __forceinline__ void gload_lds16(const void* g, void* l) {
    __builtin_amdgcn_global_load_lds(
        (const __attribute__((address_space(1))) void*)g,
        (__attribute__((address_space(3))) void*)l, 16, 0, 0);
}

// ---------------- fp32 -> bf16 convert (float4 / 4 elems per thread) ----------------
__global__ __launch_bounds__(256) void cvt_kernel(
    const float* __restrict__ x, bf16* __restrict__ h, int n)
{
    int i = (blockIdx.x * 256 + threadIdx.x) * 4;
    if (i < n) {
        const float4 v = *(const float4*)(x + i);
        uint2 o;
        o.x = pack_bf2(v.x, v.y);
        o.y = pack_bf2(v.z, v.w);
        *(uint2*)((unsigned short*)h + i) = o;
    }
}

// ---------------- RMSNorm over 768: one wave per row, 12 elems/lane, 8B loads ----------------
__global__ __launch_bounds__(256) void rmsnorm_kernel(
    const bf16* __restrict__ in, const float* __restrict__ w,
    bf16* __restrict__ out, float* __restrict__ rs_out)
{
    const int row  = blockIdx.x * 4 + (threadIdx.x >> 6);
    const int lane = threadIdx.x & 63;
    const unsigned short* rp = (const unsigned short*)in + (size_t)row * DM + lane * 12;
    uint2 u0 = *(const uint2*)rp;
    uint2 u1 = *(const uint2*)(rp + 4);
    uint2 u2 = *(const uint2*)(rp + 8);
    unsigned us[6] = {u0.x, u0.y, u1.x, u1.y, u2.x, u2.y};
    float v[12];
    #pragma unroll
    for (int i = 0; i < 6; i++) {
        v[2*i]   = u2f((unsigned short)(us[i] & 0xffff));
        v[2*i+1] = u2f((unsigned short)(us[i] >> 16));
    }
    float s = 0.f;
    #pragma unroll
    for (int i = 0; i < 12; i++) s += v[i] * v[i];
    #pragma unroll
    for (int o = 32; o > 0; o >>= 1) s += __shfl_xor(s, o, 64);
    float rs = rsqrtf(s * (1.f/DM) + EPSV);
    if (rs_out && lane == 0) rs_out[row] = rs;
    if (out) {
        const float4 w0 = *(const float4*)(w + lane*12);
        const float4 w1 = *(const float4*)(w + lane*12 + 4);
        const float4 w2 = *(const float4*)(w + lane*12 + 8);
        unsigned short* op = (unsigned short*)out + (size_t)row * DM + lane * 12;
        uint2 o0, o1, o2;
        o0.x = pack_bf2(v[0]*rs*w0.x,  v[1]*rs*w0.y);
        o0.y = pack_bf2(v[2]*rs*w0.z,  v[3]*rs*w0.w);
        o1.x = pack_bf2(v[4]*rs*w1.x,  v[5]*rs*w1.y);
        o1.y = pack_bf2(v[6]*rs*w1.z,  v[7]*rs*w1.w);
        o2.x = pack_bf2(v[8]*rs*w2.x,  v[9]*rs*w2.y);
        o2.y = pack_bf2(v[10]*rs*w2.z, v[11]*rs*w2.w);
        *(uint2*)op       = o0;
        *(uint2*)(op + 4) = o1;
        *(uint2*)(op + 8) = o2;
    }
}

// ================= 256x256 8-phase MFMA GEMM (T2+T3+T4+T5) =================
// C[M,N] (op)= A[M,K] @ W[N,K]^T.  512 thr = 8 waves (2M x 4N), per-wave out
// 128x64.  BK=64 split into 2 k-slices of 32.  LDS 128KB = 2 buf x 4 regions
// (A-ks0, A-ks1, B-ks0, B-ks1; 16KB each, 256 rows x 32 k).
// Region layout (16B slots): s = row>>1 (0..127), p' = ((row&1)<<2 | chunk) ^
// (s&7), slot = s*8+p'.  -> ds_read_b128 frag reads are 2-way bank (free);
// gload_lds writes slots linearly (slot = call*512 + tid), global source
// pre-swizzled (rule #21).
// Schedule per K-tile t (4 phases, computing from buf[t&1], staging tile t+1
// into buf[~t&1]):
//  P1: ds_read B-ks0(nf0-3)+A-ks0(m0-3); stage B-ks0(t+1); bar; lgkm0; 16 MFMA; bar
//  P2: ds_read A-ks0(m4-7);  stage A-ks0(t+1); VMCNT(4); bar; lgkm0; 16 MFMA; bar
//  P3: ds_read B-ks1+A-ks1(m0-3); stage B-ks1(t+1); bar; lgkm0; 16 MFMA; bar
//  P4: ds_read A-ks1(m4-7);  stage A-ks1(t+1); VMCNT(4); bar; lgkm0; 16 MFMA; bar
// vmcnt(4) invariant: all but the 4 newest staging loads landed ->
//  P2's vmcnt guarantees tile t's B-ks1/A-ks1 (read in P3/P4);
//  P4's vmcnt guarantees tile t+1's B-ks0/A-ks0 (read in t+1 P1/P2).
// Loads are never drained to 0 in the main loop (T4); staging writes target
// the buffer fully consumed one tile ago -> no WAR hazard.
// MODE 0: C = acc ; MODE 2: C += acc ; MODE 3: C = C * silu(acc)
template<int MODE>
__global__ __launch_bounds__(512, 2) void mgemm8(
    const short* __restrict__ A, int lda,
    const short* __restrict__ W, int ldw,
    bf16* __restrict__ C, int ldc,
    int M, int N, int K)
{
    __shared__ __attribute__((aligned(16))) short lds8[65536];   // 128 KB

    // XCD-aware bijective remap (m204), bx fastest within an XCD chunk.
    const int gx = gridDim.x;
    int lid = blockIdx.y * gx + blockIdx.x;
    {
        const int nwg = gx * gridDim.y;
        const int q = nwg >> 3, r = nwg & 7;
        const int xcd = lid & 7, slot = lid >> 3;
        lid = (xcd < r ? xcd * (q + 1) : r * (q + 1) + (xcd - r) * q) + slot;
    }
    const int bm = (lid / gx) * 256;
    const int bn = (lid % gx) * 256;

    const int tid  = threadIdx.x;
    const int wave = tid >> 6;
    const int lane = tid & 63;
    const int wr   = wave >> 2;     // 0..1  (M band of 128)
    const int wc   = wave & 3;      // 0..3  (N band of 64)
    const int r15  = lane & 15;
    const int quad = lane >> 4;

    // staging decode: thread stages slot tid (rows rr) and tid+512 (rows rr+128)
    const int sp = (tid & 7) ^ ((tid >> 3) & 7);
    const int rr = 2 * (tid >> 3) + (sp >> 2);
    const int cc = (sp & 3) * 8;                    // k-chunk offset in shorts
    const size_t gA = (size_t)(bm + rr) * lda + cc;
    const size_t gB = (size_t)(bn + rr) * ldw + cc;
    const int stW = wave * 512;                     // wave slot base (shorts)

    // frag-read lane constants: offset = laneX + frag*512 (+ region base)
    const int pp = ((quad) | ((r15 & 1) << 2)) ^ ((r15 >> 1) & 7);
    const int laneA = (64 * wr + (r15 >> 1)) * 64 + pp * 8;
    const int laneB = (32 * wc + (r15 >> 1)) * 64 + pp * 8;

    floatx4 acc[8][4];
    const floatx4 zero = {0.f, 0.f, 0.f, 0.f};
    #pragma unroll
    for (int i = 0; i < 8; i++)
        #pragma unroll
        for (int j = 0; j < 4; j++) acc[i][j] = zero;

    const int NT = K / 64;

    // region bases (shorts): A-ks = ks*8192 ; B-ks = 16384 + ks*8192
    auto stageA = [&](int ks, int buf, int kt) {
        const int reg = buf * 32768 + ks * 8192;
        const size_t kb = (size_t)kt * 64 + ks * 32;
        gload_lds16(A + gA + kb,                     &lds8[reg + stW]);
        gload_lds16(A + gA + kb + (size_t)128 * lda, &lds8[reg + 4096 + stW]);
    };
    auto stageB = [&](int ks, int buf, int kt) {
        const int reg = buf * 32768 + 16384 + ks * 8192;
        const size_t kb = (size_t)kt * 64 + ks * 32;
        gload_lds16(W + gB + kb,                     &lds8[reg + stW]);
        gload_lds16(W + gB + kb + (size_t)128 * ldw, &lds8[reg + 4096 + stW]);
    };

    // prologue: stage tile 0 (c1..c8); vmcnt(4) -> B-ks0,A-ks0 landed
    stageB(0, 0, 0); stageA(0, 0, 0); stageB(1, 0, 0); stageA(1, 0, 0);
    asm volatile("s_waitcnt vmcnt(4)" ::: "memory");
    __builtin_amdgcn_s_barrier();
    __builtin_amdgcn_sched_barrier(0);

    for (int t = 0; t < NT; ++t) {
        const int cb = (t & 1) * 32768;
        const int nb = (t + 1) & 1;
        const bool st = (t + 1 < NT);
        short8 bfv[4], afA[4], afB[4];

        // ---------- P1 ----------
        #pragma unroll
        for (int nf = 0; nf < 4; nf++)
            bfv[nf] = *(const short8*)&lds8[cb + 16384 + laneB + nf*512];
        #pragma unroll
        for (int m = 0; m < 4; m++)
            afA[m] = *(const short8*)&lds8[cb + laneA + m*512];
        if (st) stageB(0, nb, t + 1);
        __builtin_amdgcn_sched_barrier(0);
        __builtin_amdgcn_s_barrier();
        asm volatile("s_waitcnt lgkmcnt(0)" ::: "memory");
        __builtin_amdgcn_sched_barrier(0);
        __builtin_amdgcn_s_setprio(1);
        #pragma unroll
        for (int m = 0; m < 4; m++)
            #pragma unroll
            for (int nf = 0; nf < 4; nf++)
                acc[m][nf] = __builtin_amdgcn_mfma_f32_16x16x32_bf16(
                    afA[m], bfv[nf], acc[m][nf], 0, 0, 0);
        __builtin_amdgcn_s_setprio(0);
        __builtin_amdgcn_sched_barrier(0);
        __builtin_amdgcn_s_barrier();

        // ---------- P2 ----------
        #pragma unroll
        for (int m = 0; m < 4; m++)
            afB[m] = *(const short8*)&lds8[cb + laneA + (m+4)*512];
        if (st) stageA(0, nb, t + 1);
        __builtin_amdgcn_sched_barrier(0);
        if (st) asm volatile("s_waitcnt vmcnt(4)" ::: "memory");
        else    asm volatile("s_waitcnt vmcnt(0)" ::: "memory");
        __builtin_amdgcn_s_barrier();
        asm volatile("s_waitcnt lgkmcnt(0)" ::: "memory");
        __builtin_amdgcn_sched_barrier(0);
        __builtin_amdgcn_s_setprio(1);
        #pragma unroll
        for (int m = 0; m < 4; m++)
            #pragma unroll
            for (int nf = 0; nf < 4; nf++)
                acc[m+4][nf] = __builtin_amdgcn_mfma_f32_16x16x32_bf16(
                    afB[m], bfv[nf], acc[m+4][nf], 0, 0, 0);
        __builtin_amdgcn_s_setprio(0);
        __builtin_amdgcn_sched_barrier(0);
        __builtin_amdgcn_s_barrier();

        // ---------- P3 ----------
        #pragma unroll
        for (int nf = 0; nf < 4; nf++)
            bfv[nf] = *(const short8*)&lds8[cb + 24576 + laneB + nf*512];
        #pragma unroll
        for (int m = 0; m < 4; m++)
            afA[m] = *(const short8*)&lds8[cb + 8192 + laneA + m*512];
        if (st) stageB(1, nb, t + 1);
        __builtin_amdgcn_sched_barrier(0);
        __builtin_amdgcn_s_barrier();
        asm volatile("s_waitcnt lgkmcnt(0)" ::: "memory");
        __builtin_amdgcn_sched_barrier(0);
        __builtin_amdgcn_s_setprio(1);
        #pragma unroll
        for (int m = 0; m < 4; m++)
            #pragma unroll
            for (int nf = 0; nf < 4; nf++)
                acc[m][nf] = __builtin_amdgcn_mfma_f32_16x16x32_bf16(
                    afA[m], bfv[nf], acc[m][nf], 0, 0, 0);
        __builtin_amdgcn_s_setprio(0);
        __builtin_amdgcn_sched_barrier(0);
        __builtin_amdgcn_s_barrier();

        // ---------- P4 ----------
        #pragma unroll
        for (int m = 0; m < 4; m++)
            afB[m] = *(const short8*)&lds8[cb + 8192 + laneA + (m+4)*512];
        if (st) stageA(1, nb, t + 1);
        __builtin_amdgcn_sched_barrier(0);
        if (st) asm volatile("s_waitcnt vmcnt(4)" ::: "memory");
        __builtin_amdgcn_s_barrier();
        asm volatile("s_waitcnt lgkmcnt(0)" ::: "memory");
        __builtin_amdgcn_sched_barrier(0);
        __builtin_amdgcn_s_setprio(1);
        #pragma unroll
        for (int m = 0; m < 4; m++)
            #pragma unroll
            for (int nf = 0; nf < 4; nf++)
                acc[m+4][nf] = __builtin_amdgcn_mfma_f32_16x16x32_bf16(
                    afB[m], bfv[nf], acc[m+4][nf], 0, 0, 0);
        __builtin_amdgcn_s_setprio(0);
        __builtin_amdgcn_sched_barrier(0);
        __builtin_amdgcn_s_barrier();
    }

    // ---- wide-store epilogue: bounce each wave's 128x64 tile through LDS ----
    short* ep = lds8 + wave * 1152;
    const int lr = lane >> 2;
    const int lc = lane & 3;
    #pragma unroll
    for (int mt = 0; mt < 8; mt++) {
        #pragma unroll
        for (int nf = 0; nf < 4; nf++)
            #pragma unroll
            for (int reg = 0; reg < 4; reg++) {
                bf16 tt = f2b(acc[mt][nf][reg]);
                ep[(quad*4 + reg)*EPS_STRIDE + nf*16 + r15] = *(short*)&tt;
            }
        short8 v0 = *(const short8*)&ep[lr*EPS_STRIDE + lc*16];
        short8 v1 = *(const short8*)&ep[lr*EPS_STRIDE + lc*16 + 8];
        int gm = bm + wr*128 + mt*16 + lr;
        int gn = bn + wc*64 + lc*16;
        if (gn < N) {
            bf16* cp = C + (size_t)gm * ldc + gn;
            if (MODE == 0) {
                *(short8*)cp       = v0;
                *(short8*)(cp + 8) = v1;
            } else {
                short8 c0 = *(const short8*)cp;
                short8 c1 = *(const short8*)(cp + 8);
                short8 o0, o1;
                #pragma unroll
                for (int j = 0; j < 8; j++) {
                    float cv0 = u2f((unsigned short)c0[j]);
                    float av0 = u2f((unsigned short)v0[j]);
                    float cv1 = u2f((unsigned short)c1[j]);
                    float av1 = u2f((unsigned short)v1[j]);
                    float rr0 = (MODE == 2) ? (cv0 + av0) : (cv0 * silu_f(av0));
                    float rr1 = (MODE == 2) ? (cv1 + av1) : (cv1 * silu_f(av1));
                    bf16 t0 = f2b(rr0), t1 = f2b(rr1);
                    o0[j] = *(short*)&t0;
                    o1[j] = *(short*)&t1;
                }
                *(short8*)cp       = o0;
                *(short8*)(cp + 8) = o1;
            }
        }
    }
}

// ---------------- split-K x_proj GEMM with fused causal conv (old verified) ----
// C partials (fp32 atomics) = silu(conv4(A)) @ W^T ; 128x128 tile, 2-barrier.
__global__ __launch_bounds__(256) void mgemm_conv(
    const short* __restrict__ A, int lda,
    const short* __restrict__ W, int ldw,
    float* __restrict__ Cf, int ldc,
    int M, int N, int K,
    const float* __restrict__ cw, const float* __restrict__ cb,
    int ksteps_per_split)
{
    __shared__ __attribute__((aligned(16))) short As[BM*BK];
    __shared__ __attribute__((aligned(16))) short Bs[BN*BK];

    const int gx = gridDim.x;
    int lid = blockIdx.y * gx + blockIdx.x;
    {
        const int nwg = gx * gridDim.y;
        const int q = nwg >> 3, r = nwg & 7;
        const int xcd = lid & 7, slot = lid >> 3;
        lid = (xcd < r ? xcd * (q + 1) : r * (q + 1) + (xcd - r) * q) + slot;
    }
    const int bm = (lid / gx) * BM;
    const int bn = (lid % gx) * BN;

    const int tid = threadIdx.x;
    const int wave = tid >> 6;
    const int lane = tid & 63;
    const int wm = (wave & 1) * 64;
    const int wn = (wave >> 1) * 64;
    const int r15 = lane & 15;
    const int quad = lane >> 4;

    int kbeg = blockIdx.z * ksteps_per_split * BK;
    int kend = kbeg + ksteps_per_split * BK;
    if (kend > K) kend = K;

    const int srow = wave*32 + (lane >> 2);
    const int swz = (lane & 3) ^ ((lane >> 3) & 3);
    int wr0 = bn + srow;      if (wr0 >= N) wr0 = N - 1;
    int wr1 = bn + srow + 16; if (wr1 >= N) wr1 = N - 1;

    floatx4 acc[4][4];
    const floatx4 zero = {0.f, 0.f, 0.f, 0.f};
    #pragma unroll
    for (int i = 0; i < 4; i++)
        #pragma unroll
        for (int j = 0; j < 4; j++) acc[i][j] = zero;

    const int kk = tid & 31;
    const int tg = tid >> 5;
    const int sA = quad;
    const int sB = quad ^ ((r15 >> 1) & 3);

    for (int k0 = kbeg; k0 < kend; k0 += BK) {
        {
            int e = k0 + kk;
            float c0 = cw[e*4+0], c1 = cw[e*4+1], c2 = cw[e*4+2], c3 = cw[e*4+3];
            float cbe = cb[e];
            int g0 = bm + tg*16;
            const unsigned short* xp = (const unsigned short*)A + (size_t)g0 * lda + e;
            float p0 = 0.f, p1 = 0.f, p2 = 0.f;
            if ((g0 & (LSEQ-1)) != 0) {
                p0 = u2f(xp[-(ptrdiff_t)3*lda]);
                p1 = u2f(xp[-(ptrdiff_t)2*lda]);
                p2 = u2f(xp[-(ptrdiff_t)1*lda]);
            }
            #pragma unroll
            for (int i = 0; i < 16; i++) {
                float xt = u2f(xp[(size_t)i * lda]);
                float xv = silu_f(cbe + c0*p0 + c1*p1 + c2*p2 + c3*xt);
                p0 = p1; p1 = p2; p2 = xt;
                bf16 t = f2b(xv);
                As[(tg*16 + i)*BK + kk] = *(short*)&t;
            }
        }
        gload_lds16(W + (size_t)wr0 * ldw + k0 + swz*8, &Bs[(wave*32)*BK]);
        gload_lds16(W + (size_t)wr1 * ldw + k0 + swz*8, &Bs[(wave*32 + 16)*BK]);
        __syncthreads();

        short8 af[4], bfr[4];
        #pragma unroll
        for (int i = 0; i < 4; i++) af[i]  = *(const short8*)&As[(wm + i*16 + r15)*BK + sA*8];
        #pragma unroll
        for (int i = 0; i < 4; i++) bfr[i] = *(const short8*)&Bs[(wn + i*16 + r15)*BK + sB*8];
        #pragma unroll
        for (int mt = 0; mt < 4; mt++)
            #pragma unroll
            for (int nt = 0; nt < 4; nt++)
                acc[mt][nt] = __builtin_amdgcn_mfma_f32_16x16x32_bf16(
                    af[mt], bfr[nt], acc[mt][nt], 0, 0, 0);
        __syncthreads();
    }

    #pragma unroll
    for (int nt = 0; nt < 4; nt++) {
        int n = bn + wn + nt*16 + r15;
        if (n >= N) continue;
        #pragma unroll
        for (int mt = 0; mt < 4; mt++)
            #pragma unroll
            for (int reg = 0; reg < 4; reg++) {
                int m = bm + wm + mt*16 + quad*4 + reg;
                atomicAdd(&Cf[(size_t)m * ldc + n], acc[mt][nt][reg]);
            }
    }
}

// ---------------- chunked selective scan, no shuffles ----------------
template<int PASS>
__global__ __launch_bounds__(256) void scan_pass_kernel(
    bf16* __restrict__ xy,              // [M,1536]  xin (PASS2: y overwrites)
    const bf16* __restrict__ dbc,       // [M,80]  dt_r | B | C
    const float* __restrict__ A_log,    // [1536,16] layer slice
    const float* __restrict__ Dp,       // [1536]
    const float* __restrict__ dtw,      // [1536,48]
    const float* __restrict__ dtb,      // [1536]
    const float* __restrict__ cw,       // [1536,4]
    const float* __restrict__ cb,       // [1536]
    float* __restrict__ hst,            // [B*DI, CHK, 16]
    float* __restrict__ Ssum,           // [B*DI, CHK]
    unsigned short* __restrict__ bound) // [B*DI, CHK, 4]
{
    int e = (blockIdx.x % (DI/256)) * 256 + threadIdx.x;
    int b = (blockIdx.x / (DI/256)) & (NBATCH - 1);
    int c = blockIdx.x / ((DI/256) * NBATCH);
    int t0 = c * CLEN;

    float w[RNK];
    #pragma unroll
    for (int r = 0; r < RNK; r++) w[r] = dtw[e*RNK + r];
    float a[DS];
    #pragma unroll
    for (int n = 0; n < DS; n++) a[n] = -__expf(A_log[e*DS + n]);
    float c0 = cw[e*4+0], c1 = cw[e*4+1], c2 = cw[e*4+2], c3 = cw[e*4+3];
    float cbe = cb[e], dtbe = dtb[e], dpe = Dp[e];

    size_t sidx = ((size_t)(b*DI) + e) * CHK + c;
    float hh[DS];
    if (PASS == 1) {
        #pragma unroll
        for (int n = 0; n < DS; n++) hh[n] = 0.f;
    } else {
        #pragma unroll
        for (int n = 0; n < DS; n++) hh[n] = hst[sidx*DS + n];
    }

    unsigned short* xrow = (unsigned short*)(xy + ((size_t)(b*LSEQ) + t0) * DI + e);
    const unsigned short* drow = (const unsigned short*)(dbc + ((size_t)(b*LSEQ) + t0) * 80);

    unsigned short r0, r1, r2;
    if (PASS == 1) {
        if (c == 0) { r0 = 0; r1 = 0; r2 = 0; }
        else {
            r0 = xrow[-(ptrdiff_t)3*DI];
            r1 = xrow[-(ptrdiff_t)2*DI];
            r2 = xrow[-(ptrdiff_t)1*DI];
        }
        bound[sidx*4+0] = r0; bound[sidx*4+1] = r1; bound[sidx*4+2] = r2;
    } else {
        r0 = bound[sidx*4+0]; r1 = bound[sidx*4+1]; r2 = bound[sidx*4+2];
    }
    float p0 = u2f(r0), p1 = u2f(r1), p2 = u2f(r2);

    float S = 0.f;
    for (int t = 0; t < CLEN; t++) {
        float xt = u2f(xrow[(size_t)t * DI]);
        float xv = silu_f(cbe + c0*p0 + c1*p1 + c2*p2 + c3*xt);
        p0 = p1; p1 = p2; p2 = xt;

        uint4 q[5];
        const uint4* d4 = (const uint4*)(drow + (size_t)t * 80);
        #pragma unroll
        for (int i = 0; i < 5; i++) q[i] = d4[i];
        uint4 q2[5];
        #pragma unroll
        for (int i = 0; i < 5; i++) q2[i] = d4[5 + i];
        const unsigned short* ds = (const unsigned short*)q;
        const unsigned short* ds2 = (const unsigned short*)q2;

        float acc = dtbe;
        #pragma unroll
        for (int r = 0; r < RNK; r++) acc += w[r] * u2f(ds[r]);
        float d = (acc > 20.f) ? acc : __logf(1.f + __expf(acc));
        float dx = d * xv;
        #pragma unroll
        for (int n = 0; n < DS; n++)
            hh[n] = __expf(d * a[n]) * hh[n] + dx * u2f(ds[RNK + n]);

        if (PASS == 1) {
            S += d;
        } else {
            float y = xv * dpe;
            #pragma unroll
            for (int n = 0; n < DS; n++) y += hh[n] * u2f(ds2[n]);
            bf16 yb = f2b(y);
            xrow[(size_t)t * DI] = *(unsigned short*)&yb;
        }
    }
    if (PASS == 1) {
        #pragma unroll
        for (int n = 0; n < DS; n++) hst[sidx*DS + n] = hh[n];
        Ssum[sidx] = S;
    }
}

// ---------------- combine chunk states ----------------
__global__ __launch_bounds__(256) void scan_combine_kernel(
    float* __restrict__ hst, const float* __restrict__ Ssum,
    const float* __restrict__ A_log)
{
    int tid = blockIdx.x * 256 + threadIdx.x;
    int n = tid & 15;
    int bee = tid >> 4;
    int e = bee % DI;
    float a = -__expf(A_log[e*DS + n]);
    float run = 0.f;
    for (int c = 0; c < CHK; c++) {
        size_t idx = ((size_t)bee * CHK + c) * DS + n;
        float tmp = hst[idx];
        hst[idx] = run;
        run = tmp + __expf(a * Ssum[(size_t)bee*CHK + c]) * run;
    }
}

// ---------------- pooled[b,d] = (1/L) sum_t h[b,t,d]*rs[b,t]*wf[d] ----------------
__global__ __launch_bounds__(128) void pool_kernel(
    const bf16* __restrict__ h, const float* __restrict__ rs,
    const float* __restrict__ wf, float* __restrict__ pooled)
{
    int b = blockIdx.x, dc = blockIdx.y, tc = blockIdx.z;
    int d = dc * 128 + threadIdx.x;
    float s = 0.f;
    int t0 = tc * 128;
    for (int t = t0; t < t0 + 128; t++) {
        int row = b * LSEQ + t;
        s += b2f(h[(size_t)row * DM + d]) * rs[row];
    }
    atomicAdd(&pooled[b * DM + d], s * wf[d] * (1.f / LSEQ));
}

// ---------------- classifier head + log_softmax + NLL ----------------
__global__ __launch_bounds__(128) void head_kernel(
    const float* __restrict__ pooled, const float* __restrict__ cls_w,
    const float* __restrict__ cls_b, const int* __restrict__ labels,
    float* __restrict__ out)
{
    __shared__ float lg[80];
    int tid = threadIdx.x;
    if (tid < 80) {
        int b = tid / 10, c = tid % 10;
        float s = cls_b[c];
        for (int d = 0; d < DM; d++) s += pooled[b * DM + d] * cls_w[c * DM + d];
        lg[tid] = s;
    }
    __syncthreads();
    if (tid == 0) {
        float loss = 0.f;
        for (int b = 0; b < NBATCH; b++) {
            float mx = -1e30f;
            for (int c = 0; c < 10; c++) mx = fmaxf(mx, lg[b*10+c]);
            float se = 0.f;
            for (int c = 0; c < 10; c++) se += expf(lg[b*10+c] - mx);
            float lse = mx + logf(se);
            loss -= (lg[b*10 + labels[b]] - lse);
            for (int c = 0; c < 10; c++) out[b*10+c] = lg[b*10+c];
        }
        out[80] = loss / NBATCH;
    }
}

extern "C" void kernel_launch(void* const* d_in, const int* in_sizes, int n_in,
                              void* d_out, int out_size, void* d_ws, size_t ws_size,
                              hipStream_t stream) {
    const float* x          = (const float*)d_in[0];
    const int*   labels     = (const int*)d_in[1];
    const float* in_proj_w  = (const float*)d_in[2];
    const float* conv_w     = (const float*)d_in[3];
    const float* conv_b     = (const float*)d_in[4];
    const float* x_proj_w   = (const float*)d_in[5];
    const float* dt_w       = (const float*)d_in[6];
    const float* dt_b       = (const float*)d_in[7];
    const float* A_log      = (const float*)d_in[8];
    const float* D_param    = (const float*)d_in[9];
    const float* out_proj_w = (const float*)d_in[10];
    const float* norm_w     = (const float*)d_in[11];
    const float* normf_w    = (const float*)d_in[12];
    const float* cls_w      = (const float*)d_in[13];
    const float* cls_b      = (const float*)d_in[14];
    float* out = (float*)d_out;

    // workspace layout (~127 MB total)
    char* p = (char*)d_ws;
    bf16* h   = (bf16*)p;                 p += (size_t)MTOK * DM * 2;        // 25.2 MB
    bf16* xn  = (bf16*)p;                 p += (size_t)MTOK * DM * 2;        // 25.2 MB
    bf16* xy  = (bf16*)p;                 p += (size_t)MTOK * DI * 2;        // 50.3 MB (xin -> y)
    bf16* dbc = (bf16*)p;                 p += (size_t)MTOK * 80 * 2;        // 2.6 MB
    float* dbcf = (float*)p;              p += (size_t)MTOK * 80 * 4;        // 5.2 MB (split-K fp32 acc)
    float* hst = (float*)p;               p += (size_t)NBATCH*DI*CHK*DS*4;   // 12.6 MB
    float* Ssum = (float*)p;              p += (size_t)NBATCH*DI*CHK*4;      // 0.8 MB
    unsigned short* bound = (unsigned short*)p; p += (size_t)NBATCH*DI*CHK*4*2; // 1.6 MB
    float* rsb    = (float*)p;            p += (size_t)MTOK * 4;
    float* pooled = (float*)p;            p += NBATCH * DM * 4;
    short* inw_b = (short*)p;             p += (size_t)2*DI*DM * 2;          // 4.7 MB (per-layer)
    short* xw_b  = (short*)p;             p += (size_t)80*DI * 2;            // 0.25 MB
    short* ow_b  = (short*)p;             p += (size_t)DM*DI * 2;            // 2.4 MB

    cvt_kernel<<<(MTOK * DM) / 1024, 256, 0, stream>>>(x, h, MTOK * DM);
    hipMemsetAsync(pooled, 0, NBATCH * DM * sizeof(float), stream);

    int scan_grid = (DI/256) * NBATCH * CHK;   // 768

    for (int l = 0; l < 4; l++) {
        const float* inw = in_proj_w + (size_t)l * 2 * DI * DM;
        const float* cwl = conv_w + (size_t)l * DI * 4;
        const float* cbl = conv_b + (size_t)l * DI;
        const float* xwl = x_proj_w + (size_t)l * (RNK + 2*DS) * DI;
        const float* dwl = dt_w + (size_t)l * DI * RNK;
        const float* dbl = dt_b + (size_t)l * DI;
        const float* All = A_log + (size_t)l * DI * DS;
        const float* Dpl = D_param + (size_t)l * DI;
        const float* owl = out_proj_w + (size_t)l * DM * DI;

        // per-layer weight conversion fp32 -> bf16 (reused buffers)
        cvt_kernel<<<(2*DI*DM)/1024, 256, 0, stream>>>(inw, (bf16*)inw_b, 2*DI*DM);
        cvt_kernel<<<(80*DI)/1024, 256, 0, stream>>>(xwl, (bf16*)xw_b, 80*DI);
        cvt_kernel<<<(DM*DI)/1024, 256, 0, stream>>>(owl, (bf16*)ow_b, DM*DI);

        rmsnorm_kernel<<<MTOK/4, 256, 0, stream>>>(h, norm_w + (size_t)l * DM, xn, nullptr);

        // zero split-K accumulator (ws is re-poisoned 0xAA before every call)
        hipMemsetAsync(dbcf, 0, (size_t)MTOK * 80 * sizeof(float), stream);

        // xin = xn @ in_w[0:1536]^T   (256^2 8-phase MFMA)
        mgemm8<0><<<dim3(DI/256, MTOK/256), 512, 0, stream>>>(
            (const short*)xn, DM, inw_b, DM, xy, DI, MTOK, DI, DM);

        // dbc partials = silu(conv(xin)) @ xw^T   (split-K, conv fused)
        mgemm_conv<<<dim3(1, MTOK/BM, KSPLIT), 256, 0, stream>>>(
            (const short*)xy, DI, xw_b, DI, dbcf, 80, MTOK, 80, DI,
            cwl, cbl, (DI/BK)/KSPLIT);
        cvt_kernel<<<(MTOK*80)/1024, 256, 0, stream>>>(dbcf, dbc, MTOK*80);

        // chunked scan: pass1 -> combine -> pass2 (y overwrites xin in xy)
        scan_pass_kernel<1><<<scan_grid, 256, 0, stream>>>(
            xy, dbc, All, Dpl, dwl, dbl, cwl, cbl, hst, Ssum, bound);
        scan_combine_kernel<<<(NBATCH*DI*DS)/256, 256, 0, stream>>>(hst, Ssum, All);
        scan_pass_kernel<2><<<scan_grid, 256, 0, stream>>>(
            xy, dbc, All, Dpl, dwl, dbl, cwl, cbl, hst, Ssum, bound);

        // gating: y *= silu(xn @ in_w[1536:3072]^T)   (256^2 8-phase MFMA)
        mgemm8<3><<<dim3(DI/256, MTOK/256), 512, 0, stream>>>(
            (const short*)xn, DM, inw_b + (size_t)DI*DM, DM, xy, DI, MTOK, DI, DM);

        // h += y @ out_w^T   (256^2 8-phase MFMA)
        mgemm8<2><<<dim3(DM/256, MTOK/256), 512, 0, stream>>>(
            (const short*)xy, DI, ow_b, DI, h, DM, MTOK, DM, DI);
    }

    rmsnorm_kernel<<<MTOK/4, 256, 0, stream>>>(h, normf_w, nullptr, rsb);
    pool_kernel<<<dim3(NBATCH, DM/128, LSEQ/128), 128, 0, stream>>>(h, rsb, normf_w, pooled);
    head_kernel<<<1, 128, 0, stream>>>(pooled, cls_w, cls_b, labels, out);
}

// Round 6
// 1112.830 us; speedup vs baseline: 1.0489x; 1.0489x over previous
//
#include <hip/hip_runtime.h>
#include <hip/hip_bf16.h>
#include <math.h>

#define MTOK 16384      // B*L tokens
#define DM   768
#define DI   1536
#define DS   16
#define RNK  48
#define LSEQ 2048
#define NBATCH 8
#define EPSV 1e-5f
#define CHK  16         // time chunks for the scan
#define CLEN (LSEQ / CHK)
#define BM 128
#define BN 128
#define BK 32
#define KSPLIT 8        // split-K factor for the x_proj GEMM
#define EPS_STRIDE 72   // epilogue LDS row stride (shorts), 16B-aligned, conflict-light

typedef __hip_bfloat16 bf16;
typedef __attribute__((ext_vector_type(8))) short short8;
typedef __attribute__((ext_vector_type(4))) float floatx4;

__device__ __forceinline__ float b2f(bf16 v){ return __bfloat162float(v); }
__device__ __forceinline__ bf16  f2b(float v){ return __float2bfloat16(v); }
__device__ __forceinline__ float u2f(unsigned short u){
    union { unsigned int i; float f; } v; v.i = ((unsigned int)u) << 16; return v.f;
}
__device__ __forceinline__ unsigned pack_bf2(float a, float b){
    bf16 ta = f2b(a), tb = f2b(b);
    return (unsigned)(*(unsigned short*)&ta) | ((unsigned)(*(unsigned short*)&tb) << 16);
}
__device__ __forceinline__ float silu_f(float x){
    return x * __builtin_amdgcn_rcpf(1.f + __expf(-x));
}
__device__ __forceinline__ void gload_lds16(const void* g, void* l) {
    __builtin_amdgcn_global_load_lds(
        (const __attribute__((address_space(1))) void*)g,
        (__attribute__((address_space(3))) void*)l, 16, 0, 0);
}

// ---------------- fp32 -> bf16 convert (float4 / 4 elems per thread) ----------------
__global__ __launch_bounds__(256) void cvt_kernel(
    const float* __restrict__ x, bf16* __restrict__ h, int n)
{
    int i = (blockIdx.x * 256 + threadIdx.x) * 4;
    if (i < n) {
        const float4 v = *(const float4*)(x + i);
        uint2 o;
        o.x = pack_bf2(v.x, v.y);
        o.y = pack_bf2(v.z, v.w);
        *(uint2*)((unsigned short*)h + i) = o;
    }
}

// ---------------- RMSNorm over 768: one wave per row, 12 elems/lane, 8B loads ----------------
__global__ __launch_bounds__(256) void rmsnorm_kernel(
    const bf16* __restrict__ in, const float* __restrict__ w,
    bf16* __restrict__ out, float* __restrict__ rs_out)
{
    const int row  = blockIdx.x * 4 + (threadIdx.x >> 6);
    const int lane = threadIdx.x & 63;
    const unsigned short* rp = (const unsigned short*)in + (size_t)row * DM + lane * 12;
    uint2 u0 = *(const uint2*)rp;
    uint2 u1 = *(const uint2*)(rp + 4);
    uint2 u2 = *(const uint2*)(rp + 8);
    unsigned us[6] = {u0.x, u0.y, u1.x, u1.y, u2.x, u2.y};
    float v[12];
    #pragma unroll
    for (int i = 0; i < 6; i++) {
        v[2*i]   = u2f((unsigned short)(us[i] & 0xffff));
        v[2*i+1] = u2f((unsigned short)(us[i] >> 16));
    }
    float s = 0.f;
    #pragma unroll
    for (int i = 0; i < 12; i++) s += v[i] * v[i];
    #pragma unroll
    for (int o = 32; o > 0; o >>= 1) s += __shfl_xor(s, o, 64);
    float rs = rsqrtf(s * (1.f/DM) + EPSV);
    if (rs_out && lane == 0) rs_out[row] = rs;
    if (out) {
        const float4 w0 = *(const float4*)(w + lane*12);
        const float4 w1 = *(const float4*)(w + lane*12 + 4);
        const float4 w2 = *(const float4*)(w + lane*12 + 8);
        unsigned short* op = (unsigned short*)out + (size_t)row * DM + lane * 12;
        uint2 o0, o1, o2;
        o0.x = pack_bf2(v[0]*rs*w0.x,  v[1]*rs*w0.y);
        o0.y = pack_bf2(v[2]*rs*w0.z,  v[3]*rs*w0.w);
        o1.x = pack_bf2(v[4]*rs*w1.x,  v[5]*rs*w1.y);
        o1.y = pack_bf2(v[6]*rs*w1.z,  v[7]*rs*w1.w);
        o2.x = pack_bf2(v[8]*rs*w2.x,  v[9]*rs*w2.y);
        o2.y = pack_bf2(v[10]*rs*w2.z, v[11]*rs*w2.w);
        *(uint2*)op       = o0;
        *(uint2*)(op + 4) = o1;
        *(uint2*)(op + 8) = o2;
    }
}

// ---------------- bf16 MFMA GEMM: C[M,N] (op)= A[M,K] @ W[N,K]^T ----------------
// 128x128 tile, BK=32, 4 waves 2x2, each wave 4x4 mfma_f32_16x16x32_bf16.
// r6: 3-buffer LDS ring (48KB -> 3 blocks/CU), counted vmcnt(4), ONE raw
// barrier per K-tile, no full vmcnt(0) drain in the main loop (T4).
// Per window t: ds_read frags from buf[t%3]; stage tile t+2 into buf[(t+2)%3]
// (4 gload_lds16/thread); MFMA 16 (setprio 1); vmcnt(4); s_barrier.
// Invariants: at window t start, outstanding = tile t+1's 4 loads. Window
// issues t+2's 4 -> 8 outstanding; vmcnt(4) drains t+1's (consumed next
// window, made cross-wave visible by the barrier). WAR: buf[(t+2)%3] was
// last READ in window t-1, whose reads completed before barrier B(t-1);
// stage of t+2 is issued after B(t-1). NK divisible by 3 for all shapes used
// (24, 48) -> last tile reads buf2, epilogue bounce uses buf0 region.
// XCD-aware bijective block remap + verified XOR LDS swizzle (r3 counters:
// FETCH 127->55MB, conflicts 4.9M->197K).
// MODE 0: C = acc ; MODE 2: C += acc ; MODE 3: C = C * silu(acc)
template<int MODE>
__global__ __launch_bounds__(256) void mgemm(
    const short* __restrict__ A, int lda,
    const short* __restrict__ W, int ldw,
    bf16* __restrict__ C, int ldc,
    int M, int N, int K)
{
    __shared__ __attribute__((aligned(16))) short lds[3 * 8192];   // 48 KB

    const int gx = gridDim.x;
    int lid = blockIdx.y * gx + blockIdx.x;
    {
        const int nwg = gx * gridDim.y;
        const int q = nwg >> 3, r = nwg & 7;
        const int xcd = lid & 7, slot = lid >> 3;
        lid = (xcd < r ? xcd * (q + 1) : r * (q + 1) + (xcd - r) * q) + slot;
    }
    const int bm = (lid / gx) * BM;
    const int bn = (lid % gx) * BN;

    const int tid = threadIdx.x;
    const int wave = tid >> 6;
    const int lane = tid & 63;
    const int wm = (wave & 1) * 64;
    const int wn = (wave >> 1) * 64;
    const int r15 = lane & 15;
    const int quad = lane >> 4;

    const int srow = wave*32 + (lane >> 2);
    const int swz = (lane & 3) ^ ((lane >> 3) & 3);   // staging chunk swizzle
    int wr0 = bn + srow;      if (wr0 >= N) wr0 = N - 1;
    int wr1 = bn + srow + 16; if (wr1 >= N) wr1 = N - 1;

    const short* Ab  = A + (size_t)(bm + srow) * lda + swz*8;
    const short* Ab1 = A + (size_t)(bm + srow + 16) * lda + swz*8;
    const short* Wb0 = W + (size_t)wr0 * ldw + swz*8;
    const short* Wb1 = W + (size_t)wr1 * ldw + swz*8;
    const int dA0 = (wave*32)*BK;          // wave-uniform LDS dest offsets
    const int dA1 = (wave*32 + 16)*BK;
    const int dB0 = 4096 + (wave*32)*BK;
    const int dB1 = 4096 + (wave*32 + 16)*BK;

    floatx4 acc[4][4];
    const floatx4 zero = {0.f, 0.f, 0.f, 0.f};
    #pragma unroll
    for (int i = 0; i < 4; i++)
        #pragma unroll
        for (int j = 0; j < 4; j++) acc[i][j] = zero;

    const int sA = quad ^ ((r15 >> 1) & 3);   // fragment-read swizzle
    const int sB = sA;

    const int NK = K / BK;

    auto STAGE = [&](int buf, int kt) {
        const int bb = buf * 8192;
        const size_t kc = (size_t)kt * BK;
        gload_lds16(Ab  + kc, &lds[bb + dA0]);
        gload_lds16(Ab1 + kc, &lds[bb + dA1]);
        gload_lds16(Wb0 + kc, &lds[bb + dB0]);
        gload_lds16(Wb1 + kc, &lds[bb + dB1]);
    };

    // prologue: stage tiles 0,1 (8 loads); vmcnt(4) -> tile 0 landed
    STAGE(0, 0); STAGE(1, 1);
    asm volatile("s_waitcnt vmcnt(4)" ::: "memory");
    __builtin_amdgcn_s_barrier();
    __builtin_amdgcn_sched_barrier(0);

    for (int t = 0; t < NK; ++t) {
        const short* As = &lds[(t % 3) * 8192];
        const short* Bs = As + 4096;

        short8 af[4], bfr[4];
        #pragma unroll
        for (int i = 0; i < 4; i++) af[i]  = *(const short8*)&As[(wm + i*16 + r15)*BK + sA*8];
        #pragma unroll
        for (int i = 0; i < 4; i++) bfr[i] = *(const short8*)&Bs[(wn + i*16 + r15)*BK + sB*8];

        if (t + 2 < NK) STAGE((t + 2) % 3, t + 2);

        __builtin_amdgcn_s_setprio(1);
        #pragma unroll
        for (int mt = 0; mt < 4; mt++)
            #pragma unroll
            for (int nt = 0; nt < 4; nt++)
                acc[mt][nt] = __builtin_amdgcn_mfma_f32_16x16x32_bf16(
                    af[mt], bfr[nt], acc[mt][nt], 0, 0, 0);
        __builtin_amdgcn_s_setprio(0);

        if (t + 2 < NK)      asm volatile("s_waitcnt vmcnt(4)" ::: "memory");
        else if (t + 1 < NK) asm volatile("s_waitcnt vmcnt(0)" ::: "memory");
        __builtin_amdgcn_s_barrier();
        __builtin_amdgcn_sched_barrier(0);
    }

    // ---- wide-store epilogue: bounce each wave's 64x64 tile through LDS ----
    short* ep = lds + ((wave & 2) ? 4096 : 0) + (wave & 1) * 1152;
    const int lr = lane >> 2;
    const int lc = lane & 3;
    #pragma unroll
    for (int mt = 0; mt < 4; mt++) {
        #pragma unroll
        for (int nt = 0; nt < 4; nt++)
            #pragma unroll
            for (int reg = 0; reg < 4; reg++) {
                bf16 t = f2b(acc[mt][nt][reg]);
                ep[(quad*4 + reg)*EPS_STRIDE + nt*16 + r15] = *(short*)&t;
            }
        short8 v0 = *(const short8*)&ep[lr*EPS_STRIDE + lc*16];
        short8 v1 = *(const short8*)&ep[lr*EPS_STRIDE + lc*16 + 8];
        int gm = bm + wm + mt*16 + lr;
        int gn = bn + wn + lc*16;
        if (gn < N) {
            bf16* cp = C + (size_t)gm * ldc + gn;
            if (MODE == 0) {
                *(short8*)cp       = v0;
                *(short8*)(cp + 8) = v1;
            } else {
                short8 c0 = *(const short8*)cp;
                short8 c1 = *(const short8*)(cp + 8);
                short8 o0, o1;
                #pragma unroll
                for (int j = 0; j < 8; j++) {
                    float cv0 = u2f((unsigned short)c0[j]);
                    float av0 = u2f((unsigned short)v0[j]);
                    float cv1 = u2f((unsigned short)c1[j]);
                    float av1 = u2f((unsigned short)v1[j]);
                    float r0 = (MODE == 2) ? (cv0 + av0) : (cv0 * silu_f(av0));
                    float r1 = (MODE == 2) ? (cv1 + av1) : (cv1 * silu_f(av1));
                    bf16 t0 = f2b(r0), t1 = f2b(r1);
                    o0[j] = *(short*)&t0;
                    o1[j] = *(short*)&t1;
                }
                *(short8*)cp       = o0;
                *(short8*)(cp + 8) = o1;
            }
        }
    }
}

// ---------------- split-K x_proj GEMM with fused causal conv (old verified) ----
__global__ __launch_bounds__(256) void mgemm_conv(
    const short* __restrict__ A, int lda,
    const short* __restrict__ W, int ldw,
    float* __restrict__ Cf, int ldc,
    int M, int N, int K,
    const float* __restrict__ cw, const float* __restrict__ cb,
    int ksteps_per_split)
{
    __shared__ __attribute__((aligned(16))) short As[BM*BK];
    __shared__ __attribute__((aligned(16))) short Bs[BN*BK];

    const int gx = gridDim.x;
    int lid = blockIdx.y * gx + blockIdx.x;
    {
        const int nwg = gx * gridDim.y;
        const int q = nwg >> 3, r = nwg & 7;
        const int xcd = lid & 7, slot = lid >> 3;
        lid = (xcd < r ? xcd * (q + 1) : r * (q + 1) + (xcd - r) * q) + slot;
    }
    const int bm = (lid / gx) * BM;
    const int bn = (lid % gx) * BN;

    const int tid = threadIdx.x;
    const int wave = tid >> 6;
    const int lane = tid & 63;
    const int wm = (wave & 1) * 64;
    const int wn = (wave >> 1) * 64;
    const int r15 = lane & 15;
    const int quad = lane >> 4;

    int kbeg = blockIdx.z * ksteps_per_split * BK;
    int kend = kbeg + ksteps_per_split * BK;
    if (kend > K) kend = K;

    const int srow = wave*32 + (lane >> 2);
    const int swz = (lane & 3) ^ ((lane >> 3) & 3);
    int wr0 = bn + srow;      if (wr0 >= N) wr0 = N - 1;
    int wr1 = bn + srow + 16; if (wr1 >= N) wr1 = N - 1;

    floatx4 acc[4][4];
    const floatx4 zero = {0.f, 0.f, 0.f, 0.f};
    #pragma unroll
    for (int i = 0; i < 4; i++)
        #pragma unroll
        for (int j = 0; j < 4; j++) acc[i][j] = zero;

    const int kk = tid & 31;
    const int tg = tid >> 5;
    const int sA = quad;
    const int sB = quad ^ ((r15 >> 1) & 3);

    for (int k0 = kbeg; k0 < kend; k0 += BK) {
        {
            int e = k0 + kk;
            float c0 = cw[e*4+0], c1 = cw[e*4+1], c2 = cw[e*4+2], c3 = cw[e*4+3];
            float cbe = cb[e];
            int g0 = bm + tg*16;
            const unsigned short* xp = (const unsigned short*)A + (size_t)g0 * lda + e;
            float p0 = 0.f, p1 = 0.f, p2 = 0.f;
            if ((g0 & (LSEQ-1)) != 0) {
                p0 = u2f(xp[-(ptrdiff_t)3*lda]);
                p1 = u2f(xp[-(ptrdiff_t)2*lda]);
                p2 = u2f(xp[-(ptrdiff_t)1*lda]);
            }
            #pragma unroll
            for (int i = 0; i < 16; i++) {
                float xt = u2f(xp[(size_t)i * lda]);
                float xv = silu_f(cbe + c0*p0 + c1*p1 + c2*p2 + c3*xt);
                p0 = p1; p1 = p2; p2 = xt;
                bf16 t = f2b(xv);
                As[(tg*16 + i)*BK + kk] = *(short*)&t;
            }
        }
        gload_lds16(W + (size_t)wr0 * ldw + k0 + swz*8, &Bs[(wave*32)*BK]);
        gload_lds16(W + (size_t)wr1 * ldw + k0 + swz*8, &Bs[(wave*32 + 16)*BK]);
        __syncthreads();

        short8 af[4], bfr[4];
        #pragma unroll
        for (int i = 0; i < 4; i++) af[i]  = *(const short8*)&As[(wm + i*16 + r15)*BK + sA*8];
        #pragma unroll
        for (int i = 0; i < 4; i++) bfr[i] = *(const short8*)&Bs[(wn + i*16 + r15)*BK + sB*8];
        #pragma unroll
        for (int mt = 0; mt < 4; mt++)
            #pragma unroll
            for (int nt = 0; nt < 4; nt++)
                acc[mt][nt] = __builtin_amdgcn_mfma_f32_16x16x32_bf16(
                    af[mt], bfr[nt], acc[mt][nt], 0, 0, 0);
        __syncthreads();
    }

    #pragma unroll
    for (int nt = 0; nt < 4; nt++) {
        int n = bn + wn + nt*16 + r15;
        if (n >= N) continue;
        #pragma unroll
        for (int mt = 0; mt < 4; mt++)
            #pragma unroll
            for (int reg = 0; reg < 4; reg++) {
                int m = bm + wm + mt*16 + quad*4 + reg;
                atomicAdd(&Cf[(size_t)m * ldc + n], acc[mt][nt][reg]);
            }
    }
}

// ---------------- chunked selective scan, no shuffles ----------------
// xld: row stride of xy (1536 unfused, 3072 fused). gate (PASS2 only): if
// nonzero, y *= silu(z) with z at column offset +1536 in the same row (the
// fused in_proj wrote [xin | z]). Safe: pass2 carries conv history p0..p2 in
// registers, so overwriting xin[t] with gated y never corrupts later reads,
// and z columns are never overwritten.
template<int PASS>
__global__ __launch_bounds__(256) void scan_pass_kernel(
    bf16* __restrict__ xy, int xld, int gate,
    const bf16* __restrict__ dbc,       // [M,80]  dt_r | B | C
    const float* __restrict__ A_log,    // [1536,16] layer slice
    const float* __restrict__ Dp,       // [1536]
    const float* __restrict__ dtw,      // [1536,48]
    const float* __restrict__ dtb,      // [1536]
    const float* __restrict__ cw,       // [1536,4]
    const float* __restrict__ cb,       // [1536]
    float* __restrict__ hst,            // [B*DI, CHK, 16]
    float* __restrict__ Ssum,           // [B*DI, CHK]
    unsigned short* __restrict__ bound) // [B*DI, CHK, 4]
{
    int e = (blockIdx.x % (DI/256)) * 256 + threadIdx.x;
    int b = (blockIdx.x / (DI/256)) & (NBATCH - 1);
    int c = blockIdx.x / ((DI/256) * NBATCH);
    int t0 = c * CLEN;

    float w[RNK];
    #pragma unroll
    for (int r = 0; r < RNK; r++) w[r] = dtw[e*RNK + r];
    float a[DS];
    #pragma unroll
    for (int n = 0; n < DS; n++) a[n] = -__expf(A_log[e*DS + n]);
    float c0 = cw[e*4+0], c1 = cw[e*4+1], c2 = cw[e*4+2], c3 = cw[e*4+3];
    float cbe = cb[e], dtbe = dtb[e], dpe = Dp[e];

    size_t sidx = ((size_t)(b*DI) + e) * CHK + c;
    float hh[DS];
    if (PASS == 1) {
        #pragma unroll
        for (int n = 0; n < DS; n++) hh[n] = 0.f;
    } else {
        #pragma unroll
        for (int n = 0; n < DS; n++) hh[n] = hst[sidx*DS + n];
    }

    unsigned short* xrow = (unsigned short*)xy + ((size_t)(b*LSEQ) + t0) * xld + e;
    const unsigned short* drow = (const unsigned short*)(dbc + ((size_t)(b*LSEQ) + t0) * 80);

    unsigned short r0, r1, r2;
    if (PASS == 1) {
        if (c == 0) { r0 = 0; r1 = 0; r2 = 0; }
        else {
            r0 = xrow[-(ptrdiff_t)3*xld];
            r1 = xrow[-(ptrdiff_t)2*xld];
            r2 = xrow[-(ptrdiff_t)1*xld];
        }
        bound[sidx*4+0] = r0; bound[sidx*4+1] = r1; bound[sidx*4+2] = r2;
    } else {
        r0 = bound[sidx*4+0]; r1 = bound[sidx*4+1]; r2 = bound[sidx*4+2];
    }
    float p0 = u2f(r0), p1 = u2f(r1), p2 = u2f(r2);

    float S = 0.f;
    for (int t = 0; t < CLEN; t++) {
        float xt = u2f(xrow[(size_t)t * xld]);
        float xv = silu_f(cbe + c0*p0 + c1*p1 + c2*p2 + c3*xt);
        p0 = p1; p1 = p2; p2 = xt;

        uint4 q[5];
        const uint4* d4 = (const uint4*)(drow + (size_t)t * 80);
        #pragma unroll
        for (int i = 0; i < 5; i++) q[i] = d4[i];
        uint4 q2[5];
        #pragma unroll
        for (int i = 0; i < 5; i++) q2[i] = d4[5 + i];
        const unsigned short* ds = (const unsigned short*)q;
        const unsigned short* ds2 = (const unsigned short*)q2;

        float acc = dtbe;
        #pragma unroll
        for (int r = 0; r < RNK; r++) acc += w[r] * u2f(ds[r]);
        float d = (acc > 20.f) ? acc : __logf(1.f + __expf(acc));
        float dx = d * xv;
        #pragma unroll
        for (int n = 0; n < DS; n++)
            hh[n] = __expf(d * a[n]) * hh[n] + dx * u2f(ds[RNK + n]);

        if (PASS == 1) {
            S += d;
        } else {
            float y = xv * dpe;
            #pragma unroll
            for (int n = 0; n < DS; n++) y += hh[n] * u2f(ds2[n]);
            if (gate) {
                float zt = u2f(xrow[(size_t)t * xld + 1536]);
                y *= silu_f(zt);
            }
            bf16 yb = f2b(y);
            xrow[(size_t)t * xld] = *(unsigned short*)&yb;
        }
    }
    if (PASS == 1) {
        #pragma unroll
        for (int n = 0; n < DS; n++) hst[sidx*DS + n] = hh[n];
        Ssum[sidx] = S;
    }
}

// ---------------- combine chunk states ----------------
__global__ __launch_bounds__(256) void scan_combine_kernel(
    float* __restrict__ hst, const float* __restrict__ Ssum,
    const float* __restrict__ A_log)
{
    int tid = blockIdx.x * 256 + threadIdx.x;
    int n = tid & 15;
    int bee = tid >> 4;
    int e = bee % DI;
    float a = -__expf(A_log[e*DS + n]);
    float run = 0.f;
    for (int c = 0; c < CHK; c++) {
        size_t idx = ((size_t)bee * CHK + c) * DS + n;
        float tmp = hst[idx];
        hst[idx] = run;
        run = tmp + __expf(a * Ssum[(size_t)bee*CHK + c]) * run;
    }
}

// ---------------- pooled[b,d] = (1/L) sum_t h[b,t,d]*rs[b,t]*wf[d] ----------------
__global__ __launch_bounds__(128) void pool_kernel(
    const bf16* __restrict__ h, const float* __restrict__ rs,
    const float* __restrict__ wf, float* __restrict__ pooled)
{
    int b = blockIdx.x, dc = blockIdx.y, tc = blockIdx.z;
    int d = dc * 128 + threadIdx.x;
    float s = 0.f;
    int t0 = tc * 128;
    for (int t = t0; t < t0 + 128; t++) {
        int row = b * LSEQ + t;
        s += b2f(h[(size_t)row * DM + d]) * rs[row];
    }
    atomicAdd(&pooled[b * DM + d], s * wf[d] * (1.f / LSEQ));
}

// ---------------- classifier head + log_softmax + NLL ----------------
__global__ __launch_bounds__(128) void head_kernel(
    const float* __restrict__ pooled, const float* __restrict__ cls_w,
    const float* __restrict__ cls_b, const int* __restrict__ labels,
    float* __restrict__ out)
{
    __shared__ float lg[80];
    int tid = threadIdx.x;
    if (tid < 80) {
        int b = tid / 10, c = tid % 10;
        float s = cls_b[c];
        for (int d = 0; d < DM; d++) s += pooled[b * DM + d] * cls_w[c * DM + d];
        lg[tid] = s;
    }
    __syncthreads();
    if (tid == 0) {
        float loss = 0.f;
        for (int b = 0; b < NBATCH; b++) {
            float mx = -1e30f;
            for (int c = 0; c < 10; c++) mx = fmaxf(mx, lg[b*10+c]);
            float se = 0.f;
            for (int c = 0; c < 10; c++) se += expf(lg[b*10+c] - mx);
            float lse = mx + logf(se);
            loss -= (lg[b*10 + labels[b]] - lse);
            for (int c = 0; c < 10; c++) out[b*10+c] = lg[b*10+c];
        }
        out[80] = loss / NBATCH;
    }
}

extern "C" void kernel_launch(void* const* d_in, const int* in_sizes, int n_in,
                              void* d_out, int out_size, void* d_ws, size_t ws_size,
                              hipStream_t stream) {
    const float* x          = (const float*)d_in[0];
    const int*   labels     = (const int*)d_in[1];
    const float* in_proj_w  = (const float*)d_in[2];
    const float* conv_w     = (const float*)d_in[3];
    const float* conv_b     = (const float*)d_in[4];
    const float* x_proj_w   = (const float*)d_in[5];
    const float* dt_w       = (const float*)d_in[6];
    const float* dt_b       = (const float*)d_in[7];
    const float* A_log      = (const float*)d_in[8];
    const float* D_param    = (const float*)d_in[9];
    const float* out_proj_w = (const float*)d_in[10];
    const float* norm_w     = (const float*)d_in[11];
    const float* normf_w    = (const float*)d_in[12];
    const float* cls_w      = (const float*)d_in[13];
    const float* cls_b      = (const float*)d_in[14];
    float* out = (float*)d_out;

    // fused path needs xz = [xin | z] at 3072 cols (~181 MB total workspace);
    // fall back to the unfused flow (separate gate GEMM) if ws is smaller.
    const size_t fixed = (size_t)MTOK*DM*2*2                 // h, xn
                       + (size_t)MTOK*80*2 + (size_t)MTOK*80*4
                       + (size_t)NBATCH*DI*CHK*DS*4 + (size_t)NBATCH*DI*CHK*4
                       + (size_t)NBATCH*DI*CHK*4*2
                       + (size_t)MTOK*4 + (size_t)NBATCH*DM*4
                       + (size_t)2*DI*DM*2 + (size_t)80*DI*2 + (size_t)DM*DI*2;
    const int fused = (ws_size >= fixed + (size_t)MTOK * (2*DI) * 2 + 1024) ? 1 : 0;
    const int XLD = fused ? 2*DI : DI;

    char* p = (char*)d_ws;
    bf16* h   = (bf16*)p;                 p += (size_t)MTOK * DM * 2;
    bf16* xn  = (bf16*)p;                 p += (size_t)MTOK * DM * 2;
    bf16* xz  = (bf16*)p;                 p += (size_t)MTOK * XLD * 2;   // [xin | z] (fused) or xin->y
    bf16* dbc = (bf16*)p;                 p += (size_t)MTOK * 80 * 2;
    float* dbcf = (float*)p;              p += (size_t)MTOK * 80 * 4;
    float* hst = (float*)p;               p += (size_t)NBATCH*DI*CHK*DS*4;
    float* Ssum = (float*)p;              p += (size_t)NBATCH*DI*CHK*4;
    unsigned short* bound = (unsigned short*)p; p += (size_t)NBATCH*DI*CHK*4*2;
    float* rsb    = (float*)p;            p += (size_t)MTOK * 4;
    float* pooled = (float*)p;            p += NBATCH * DM * 4;
    short* inw_b = (short*)p;             p += (size_t)2*DI*DM * 2;
    short* xw_b  = (short*)p;             p += (size_t)80*DI * 2;
    short* ow_b  = (short*)p;             p += (size_t)DM*DI * 2;

    cvt_kernel<<<(MTOK * DM) / 1024, 256, 0, stream>>>(x, h, MTOK * DM);
    hipMemsetAsync(pooled, 0, NBATCH * DM * sizeof(float), stream);

    int scan_grid = (DI/256) * NBATCH * CHK;   // 768

    for (int l = 0; l < 4; l++) {
        const float* inw = in_proj_w + (size_t)l * 2 * DI * DM;
        const float* cwl = conv_w + (size_t)l * DI * 4;
        const float* cbl = conv_b + (size_t)l * DI;
        const float* xwl = x_proj_w + (size_t)l * (RNK + 2*DS) * DI;
        const float* dwl = dt_w + (size_t)l * DI * RNK;
        const float* dbl = dt_b + (size_t)l * DI;
        const float* All = A_log + (size_t)l * DI * DS;
        const float* Dpl = D_param + (size_t)l * DI;
        const float* owl = out_proj_w + (size_t)l * DM * DI;

        cvt_kernel<<<(2*DI*DM)/1024, 256, 0, stream>>>(inw, (bf16*)inw_b, 2*DI*DM);
        cvt_kernel<<<(80*DI)/1024, 256, 0, stream>>>(xwl, (bf16*)xw_b, 80*DI);
        cvt_kernel<<<(DM*DI)/1024, 256, 0, stream>>>(owl, (bf16*)ow_b, DM*DI);

        rmsnorm_kernel<<<MTOK/4, 256, 0, stream>>>(h, norm_w + (size_t)l * DM, xn, nullptr);

        hipMemsetAsync(dbcf, 0, (size_t)MTOK * 80 * sizeof(float), stream);

        if (fused) {
            // xz[:, :1536] = xin, xz[:, 1536:] = z  in ONE GEMM (N=3072)
            mgemm<0><<<dim3(2*DI/BN, MTOK/BM), 256, 0, stream>>>(
                (const short*)xn, DM, inw_b, DM, xz, XLD, MTOK, 2*DI, DM);
        } else {
            mgemm<0><<<dim3(DI/BN, MTOK/BM), 256, 0, stream>>>(
                (const short*)xn, DM, inw_b, DM, xz, XLD, MTOK, DI, DM);
        }

        // dbc partials = silu(conv(xin)) @ xw^T   (split-K, conv fused)
        mgemm_conv<<<dim3(1, MTOK/BM, KSPLIT), 256, 0, stream>>>(
            (const short*)xz, XLD, xw_b, DI, dbcf, 80, MTOK, 80, DI,
            cwl, cbl, (DI/BK)/KSPLIT);
        cvt_kernel<<<(MTOK*80)/1024, 256, 0, stream>>>(dbcf, dbc, MTOK*80);

        // chunked scan: pass1 -> combine -> pass2 (pass2 fuses y *= silu(z))
        scan_pass_kernel<1><<<scan_grid, 256, 0, stream>>>(
            xz, XLD, 0, dbc, All, Dpl, dwl, dbl, cwl, cbl, hst, Ssum, bound);
        scan_combine_kernel<<<(NBATCH*DI*DS)/256, 256, 0, stream>>>(hst, Ssum, All);
        scan_pass_kernel<2><<<scan_grid, 256, 0, stream>>>(
            xz, XLD, fused, dbc, All, Dpl, dwl, dbl, cwl, cbl, hst, Ssum, bound);

        if (!fused) {
            // gating: y *= silu(xn @ in_w[1536:3072]^T)
            mgemm<3><<<dim3(DI/BN, MTOK/BM), 256, 0, stream>>>(
                (const short*)xn, DM, inw_b + (size_t)DI*DM, DM, xz, XLD, MTOK, DI, DM);
        }

        // h += y @ out_w^T
        mgemm<2><<<dim3(DM/BN, MTOK/BM), 256, 0, stream>>>(
            (const short*)xz, XLD, ow_b, DI, h, DM, MTOK, DM, DI);
    }

    rmsnorm_kernel<<<MTOK/4, 256, 0, stream>>>(h, normf_w, nullptr, rsb);
    pool_kernel<<<dim3(NBATCH, DM/128, LSEQ/128), 128, 0, stream>>>(h, rsb, normf_w, pooled);
    head_kernel<<<1, 128, 0, stream>>>(pooled, cls_w, cls_b, labels, out);
}

// Round 7
// 1102.559 us; speedup vs baseline: 1.0586x; 1.0093x over previous
//
#include <hip/hip_runtime.h>
#include <hip/hip_bf16.h>
#include <math.h>

#define MTOK 16384      // B*L tokens
#define DM   768
#define DI   1536
#define DS   16
#define RNK  48
#define LSEQ 2048
#define NBATCH 8
#define EPSV 1e-5f
#define CHK  16         // time chunks for the scan
#define CLEN (LSEQ / CHK)
#define BM 128
#define BN 128
#define BK 32
#define KSPLIT 8        // split-K factor for the x_proj GEMM
#define EPS_STRIDE 72   // epilogue LDS row stride (shorts), 16B-aligned, conflict-light

typedef __hip_bfloat16 bf16;
typedef __attribute__((ext_vector_type(8))) short short8;
typedef __attribute__((ext_vector_type(4))) float floatx4;

__device__ __forceinline__ float b2f(bf16 v){ return __bfloat162float(v); }
__device__ __forceinline__ bf16  f2b(float v){ return __float2bfloat16(v); }
__device__ __forceinline__ float u2f(unsigned short u){
    union { unsigned int i; float f; } v; v.i = ((unsigned int)u) << 16; return v.f;
}
__device__ __forceinline__ unsigned pack_bf2(float a, float b){
    bf16 ta = f2b(a), tb = f2b(b);
    return (unsigned)(*(unsigned short*)&ta) | ((unsigned)(*(unsigned short*)&tb) << 16);
}
__device__ __forceinline__ float silu_f(float x){
    return x * __builtin_amdgcn_rcpf(1.f + __expf(-x));
}
__device__ __forceinline__ void gload_lds16(const void* g, void* l) {
    __builtin_amdgcn_global_load_lds(
        (const __attribute__((address_space(1))) void*)g,
        (__attribute__((address_space(3))) void*)l, 16, 0, 0);
}

// ---------------- fp32 -> bf16 convert (float4 / 4 elems per thread) ----------------
__global__ __launch_bounds__(256) void cvt_kernel(
    const float* __restrict__ x, bf16* __restrict__ h, int n)
{
    int i = (blockIdx.x * 256 + threadIdx.x) * 4;
    if (i < n) {
        const float4 v = *(const float4*)(x + i);
        uint2 o;
        o.x = pack_bf2(v.x, v.y);
        o.y = pack_bf2(v.z, v.w);
        *(uint2*)((unsigned short*)h + i) = o;
    }
}

// ---------------- RMSNorm over 768: one wave per row, 12 elems/lane, 8B loads ----------------
__global__ __launch_bounds__(256) void rmsnorm_kernel(
    const bf16* __restrict__ in, const float* __restrict__ w,
    bf16* __restrict__ out, float* __restrict__ rs_out)
{
    const int row  = blockIdx.x * 4 + (threadIdx.x >> 6);
    const int lane = threadIdx.x & 63;
    const unsigned short* rp = (const unsigned short*)in + (size_t)row * DM + lane * 12;
    uint2 u0 = *(const uint2*)rp;
    uint2 u1 = *(const uint2*)(rp + 4);
    uint2 u2 = *(const uint2*)(rp + 8);
    unsigned us[6] = {u0.x, u0.y, u1.x, u1.y, u2.x, u2.y};
    float v[12];
    #pragma unroll
    for (int i = 0; i < 6; i++) {
        v[2*i]   = u2f((unsigned short)(us[i] & 0xffff));
        v[2*i+1] = u2f((unsigned short)(us[i] >> 16));
    }
    float s = 0.f;
    #pragma unroll
    for (int i = 0; i < 12; i++) s += v[i] * v[i];
    #pragma unroll
    for (int o = 32; o > 0; o >>= 1) s += __shfl_xor(s, o, 64);
    float rs = rsqrtf(s * (1.f/DM) + EPSV);
    if (rs_out && lane == 0) rs_out[row] = rs;
    if (out) {
        const float4 w0 = *(const float4*)(w + lane*12);
        const float4 w1 = *(const float4*)(w + lane*12 + 4);
        const float4 w2 = *(const float4*)(w + lane*12 + 8);
        unsigned short* op = (unsigned short*)out + (size_t)row * DM + lane * 12;
        uint2 o0, o1, o2;
        o0.x = pack_bf2(v[0]*rs*w0.x,  v[1]*rs*w0.y);
        o0.y = pack_bf2(v[2]*rs*w0.z,  v[3]*rs*w0.w);
        o1.x = pack_bf2(v[4]*rs*w1.x,  v[5]*rs*w1.y);
        o1.y = pack_bf2(v[6]*rs*w1.z,  v[7]*rs*w1.w);
        o2.x = pack_bf2(v[8]*rs*w2.x,  v[9]*rs*w2.y);
        o2.y = pack_bf2(v[10]*rs*w2.z, v[11]*rs*w2.w);
        *(uint2*)op       = o0;
        *(uint2*)(op + 4) = o1;
        *(uint2*)(op + 8) = o2;
    }
}

// ---------------- bf16 MFMA GEMM: C[M,N] (op)= A[M,K] @ W[N,K]^T ----------------
// 128x128 tile, BK=32, 4 waves 2x2, 3-buffer LDS ring (48KB), counted
// vmcnt(4), ONE raw barrier per K-tile (r6: verified 682 TF on N=3072).
// r7: L2 supertile remap. Per XCD, bn is processed in chunks of CW=12 panels
// (W chunk 2.35MB + A panel < 4MB L2); all Rx bm-rows iterate within a chunk.
// -> W fetched once per XCD (was once per bm-row; FETCH 191MB of which ~150MB
// was W re-fetch). Falls back to the m204 linear map if the grid doesn't
// divide evenly. Out_proj (gx=6) and unfused (gx=12) reduce to CW=gx =
// previous ordering (no behavior change there).
// MODE 0: C = acc ; MODE 2: C += acc ; MODE 3: C = C * silu(acc)
template<int MODE>
__global__ __launch_bounds__(256) void mgemm(
    const short* __restrict__ A, int lda,
    const short* __restrict__ W, int ldw,
    bf16* __restrict__ C, int ldc,
    int M, int N, int K)
{
    __shared__ __attribute__((aligned(16))) short lds[3 * 8192];   // 48 KB

    const int gx = gridDim.x;
    const int lid0 = blockIdx.y * gx + blockIdx.x;
    const int nwg = gx * gridDim.y;
    int bm, bn;
    const int nper = nwg >> 3;
    if ((nwg & 7) == 0 && nper % gx == 0) {
        // supertile: XCD owns bm rows [xcd*Rx, (xcd+1)*Rx); bn in CW chunks
        const int xcd = lid0 & 7, s = lid0 >> 3;
        const int Rx = nper / gx;
        const int CW = (gx % 12 == 0) ? 12 : gx;
        const int ch = s / (Rx * CW);
        const int rem = s - ch * (Rx * CW);
        bm = (xcd * Rx + rem / CW) * BM;
        bn = (ch * CW + rem % CW) * BN;
    } else {
        const int q = nwg >> 3, r = nwg & 7;
        const int xcd = lid0 & 7, slot = lid0 >> 3;
        int lid = (xcd < r ? xcd * (q + 1) : r * (q + 1) + (xcd - r) * q) + slot;
        bm = (lid / gx) * BM;
        bn = (lid % gx) * BN;
    }

    const int tid = threadIdx.x;
    const int wave = tid >> 6;
    const int lane = tid & 63;
    const int wm = (wave & 1) * 64;
    const int wn = (wave >> 1) * 64;
    const int r15 = lane & 15;
    const int quad = lane >> 4;

    const int srow = wave*32 + (lane >> 2);
    const int swz = (lane & 3) ^ ((lane >> 3) & 3);   // staging chunk swizzle
    int wr0 = bn + srow;      if (wr0 >= N) wr0 = N - 1;
    int wr1 = bn + srow + 16; if (wr1 >= N) wr1 = N - 1;

    const short* Ab  = A + (size_t)(bm + srow) * lda + swz*8;
    const short* Ab1 = A + (size_t)(bm + srow + 16) * lda + swz*8;
    const short* Wb0 = W + (size_t)wr0 * ldw + swz*8;
    const short* Wb1 = W + (size_t)wr1 * ldw + swz*8;
    const int dA0 = (wave*32)*BK;          // wave-uniform LDS dest offsets
    const int dA1 = (wave*32 + 16)*BK;
    const int dB0 = 4096 + (wave*32)*BK;
    const int dB1 = 4096 + (wave*32 + 16)*BK;

    floatx4 acc[4][4];
    const floatx4 zero = {0.f, 0.f, 0.f, 0.f};
    #pragma unroll
    for (int i = 0; i < 4; i++)
        #pragma unroll
        for (int j = 0; j < 4; j++) acc[i][j] = zero;

    const int sA = quad ^ ((r15 >> 1) & 3);   // fragment-read swizzle
    const int sB = sA;

    const int NK = K / BK;

    auto STAGE = [&](int buf, int kt) {
        const int bb = buf * 8192;
        const size_t kc = (size_t)kt * BK;
        gload_lds16(Ab  + kc, &lds[bb + dA0]);
        gload_lds16(Ab1 + kc, &lds[bb + dA1]);
        gload_lds16(Wb0 + kc, &lds[bb + dB0]);
        gload_lds16(Wb1 + kc, &lds[bb + dB1]);
    };

    // prologue: stage tiles 0,1 (8 loads); vmcnt(4) -> tile 0 landed
    STAGE(0, 0); STAGE(1, 1);
    asm volatile("s_waitcnt vmcnt(4)" ::: "memory");
    __builtin_amdgcn_s_barrier();
    __builtin_amdgcn_sched_barrier(0);

    for (int t = 0; t < NK; ++t) {
        const short* As = &lds[(t % 3) * 8192];
        const short* Bs = As + 4096;

        short8 af[4], bfr[4];
        #pragma unroll
        for (int i = 0; i < 4; i++) af[i]  = *(const short8*)&As[(wm + i*16 + r15)*BK + sA*8];
        #pragma unroll
        for (int i = 0; i < 4; i++) bfr[i] = *(const short8*)&Bs[(wn + i*16 + r15)*BK + sB*8];

        if (t + 2 < NK) STAGE((t + 2) % 3, t + 2);

        __builtin_amdgcn_s_setprio(1);
        #pragma unroll
        for (int mt = 0; mt < 4; mt++)
            #pragma unroll
            for (int nt = 0; nt < 4; nt++)
                acc[mt][nt] = __builtin_amdgcn_mfma_f32_16x16x32_bf16(
                    af[mt], bfr[nt], acc[mt][nt], 0, 0, 0);
        __builtin_amdgcn_s_setprio(0);

        if (t + 2 < NK)      asm volatile("s_waitcnt vmcnt(4)" ::: "memory");
        else if (t + 1 < NK) asm volatile("s_waitcnt vmcnt(0)" ::: "memory");
        __builtin_amdgcn_s_barrier();
        __builtin_amdgcn_sched_barrier(0);
    }

    // ---- wide-store epilogue: bounce each wave's 64x64 tile through LDS ----
    short* ep = lds + ((wave & 2) ? 4096 : 0) + (wave & 1) * 1152;
    const int lr = lane >> 2;
    const int lc = lane & 3;
    #pragma unroll
    for (int mt = 0; mt < 4; mt++) {
        #pragma unroll
        for (int nt = 0; nt < 4; nt++)
            #pragma unroll
            for (int reg = 0; reg < 4; reg++) {
                bf16 t = f2b(acc[mt][nt][reg]);
                ep[(quad*4 + reg)*EPS_STRIDE + nt*16 + r15] = *(short*)&t;
            }
        short8 v0 = *(const short8*)&ep[lr*EPS_STRIDE + lc*16];
        short8 v1 = *(const short8*)&ep[lr*EPS_STRIDE + lc*16 + 8];
        int gm = bm + wm + mt*16 + lr;
        int gn = bn + wn + lc*16;
        if (gn < N) {
            bf16* cp = C + (size_t)gm * ldc + gn;
            if (MODE == 0) {
                *(short8*)cp       = v0;
                *(short8*)(cp + 8) = v1;
            } else {
                short8 c0 = *(const short8*)cp;
                short8 c1 = *(const short8*)(cp + 8);
                short8 o0, o1;
                #pragma unroll
                for (int j = 0; j < 8; j++) {
                    float cv0 = u2f((unsigned short)c0[j]);
                    float av0 = u2f((unsigned short)v0[j]);
                    float cv1 = u2f((unsigned short)c1[j]);
                    float av1 = u2f((unsigned short)v1[j]);
                    float r0 = (MODE == 2) ? (cv0 + av0) : (cv0 * silu_f(av0));
                    float r1 = (MODE == 2) ? (cv1 + av1) : (cv1 * silu_f(av1));
                    bf16 t0 = f2b(r0), t1 = f2b(r1);
                    o0[j] = *(short*)&t0;
                    o1[j] = *(short*)&t1;
                }
                *(short8*)cp       = o0;
                *(short8*)(cp + 8) = o1;
            }
        }
    }
}

// ---------------- split-K x_proj GEMM with fused causal conv (old verified) ----
__global__ __launch_bounds__(256) void mgemm_conv(
    const short* __restrict__ A, int lda,
    const short* __restrict__ W, int ldw,
    float* __restrict__ Cf, int ldc,
    int M, int N, int K,
    const float* __restrict__ cw, const float* __restrict__ cb,
    int ksteps_per_split)
{
    __shared__ __attribute__((aligned(16))) short As[BM*BK];
    __shared__ __attribute__((aligned(16))) short Bs[BN*BK];

    const int gx = gridDim.x;
    int lid = blockIdx.y * gx + blockIdx.x;
    {
        const int nwg = gx * gridDim.y;
        const int q = nwg >> 3, r = nwg & 7;
        const int xcd = lid & 7, slot = lid >> 3;
        lid = (xcd < r ? xcd * (q + 1) : r * (q + 1) + (xcd - r) * q) + slot;
    }
    const int bm = (lid / gx) * BM;
    const int bn = (lid % gx) * BN;

    const int tid = threadIdx.x;
    const int wave = tid >> 6;
    const int lane = tid & 63;
    const int wm = (wave & 1) * 64;
    const int wn = (wave >> 1) * 64;
    const int r15 = lane & 15;
    const int quad = lane >> 4;

    int kbeg = blockIdx.z * ksteps_per_split * BK;
    int kend = kbeg + ksteps_per_split * BK;
    if (kend > K) kend = K;

    const int srow = wave*32 + (lane >> 2);
    const int swz = (lane & 3) ^ ((lane >> 3) & 3);
    int wr0 = bn + srow;      if (wr0 >= N) wr0 = N - 1;
    int wr1 = bn + srow + 16; if (wr1 >= N) wr1 = N - 1;

    floatx4 acc[4][4];
    const floatx4 zero = {0.f, 0.f, 0.f, 0.f};
    #pragma unroll
    for (int i = 0; i < 4; i++)
        #pragma unroll
        for (int j = 0; j < 4; j++) acc[i][j] = zero;

    const int kk = tid & 31;
    const int tg = tid >> 5;
    const int sA = quad;
    const int sB = quad ^ ((r15 >> 1) & 3);

    for (int k0 = kbeg; k0 < kend; k0 += BK) {
        {
            int e = k0 + kk;
            float c0 = cw[e*4+0], c1 = cw[e*4+1], c2 = cw[e*4+2], c3 = cw[e*4+3];
            float cbe = cb[e];
            int g0 = bm + tg*16;
            const unsigned short* xp = (const unsigned short*)A + (size_t)g0 * lda + e;
            float p0 = 0.f, p1 = 0.f, p2 = 0.f;
            if ((g0 & (LSEQ-1)) != 0) {
                p0 = u2f(xp[-(ptrdiff_t)3*lda]);
                p1 = u2f(xp[-(ptrdiff_t)2*lda]);
                p2 = u2f(xp[-(ptrdiff_t)1*lda]);
            }
            #pragma unroll
            for (int i = 0; i < 16; i++) {
                float xt = u2f(xp[(size_t)i * lda]);
                float xv = silu_f(cbe + c0*p0 + c1*p1 + c2*p2 + c3*xt);
                p0 = p1; p1 = p2; p2 = xt;
                bf16 t = f2b(xv);
                As[(tg*16 + i)*BK + kk] = *(short*)&t;
            }
        }
        gload_lds16(W + (size_t)wr0 * ldw + k0 + swz*8, &Bs[(wave*32)*BK]);
        gload_lds16(W + (size_t)wr1 * ldw + k0 + swz*8, &Bs[(wave*32 + 16)*BK]);
        __syncthreads();

        short8 af[4], bfr[4];
        #pragma unroll
        for (int i = 0; i < 4; i++) af[i]  = *(const short8*)&As[(wm + i*16 + r15)*BK + sA*8];
        #pragma unroll
        for (int i = 0; i < 4; i++) bfr[i] = *(const short8*)&Bs[(wn + i*16 + r15)*BK + sB*8];
        #pragma unroll
        for (int mt = 0; mt < 4; mt++)
            #pragma unroll
            for (int nt = 0; nt < 4; nt++)
                acc[mt][nt] = __builtin_amdgcn_mfma_f32_16x16x32_bf16(
                    af[mt], bfr[nt], acc[mt][nt], 0, 0, 0);
        __syncthreads();
    }

    #pragma unroll
    for (int nt = 0; nt < 4; nt++) {
        int n = bn + wn + nt*16 + r15;
        if (n >= N) continue;
        #pragma unroll
        for (int mt = 0; mt < 4; mt++)
            #pragma unroll
            for (int reg = 0; reg < 4; reg++) {
                int m = bm + wm + mt*16 + quad*4 + reg;
                atomicAdd(&Cf[(size_t)m * ldc + n], acc[mt][nt][reg]);
            }
    }
}

// ---------------- chunked selective scan, no shuffles ----------------
// xld: row stride of xy (1536 unfused, 3072 fused). gate (PASS2 only): if
// nonzero, y *= silu(z) with z at column offset +1536 in the same row.
// r7: fast-exp path. The problem's A_log is log(1..16) broadcast, so
// a[n] == -(n+1) exactly and exp(d*a[n]) == r^(n+1) with r = exp(-d):
// 16 quarter-rate v_exp -> 1 v_exp + 15 full-rate muls per step. The path is
// VERIFIED AT RUNTIME per-thread (tolerance check vs -(n+1)); any input
// without this structure takes the exact path. r^n powering error ~16 ulp of
// hw exp ~= 2e-6 relative -- negligible vs bf16 rounding (4e-3).
template<int PASS>
__global__ __launch_bounds__(256) void scan_pass_kernel(
    bf16* __restrict__ xy, int xld, int gate,
    const bf16* __restrict__ dbc,       // [M,80]  dt_r | B | C
    const float* __restrict__ A_log,    // [1536,16] layer slice
    const float* __restrict__ Dp,       // [1536]
    const float* __restrict__ dtw,      // [1536,48]
    const float* __restrict__ dtb,      // [1536]
    const float* __restrict__ cw,       // [1536,4]
    const float* __restrict__ cb,       // [1536]
    float* __restrict__ hst,            // [B*DI, CHK, 16]
    float* __restrict__ Ssum,           // [B*DI, CHK]
    unsigned short* __restrict__ bound) // [B*DI, CHK, 4]
{
    int e = (blockIdx.x % (DI/256)) * 256 + threadIdx.x;
    int b = (blockIdx.x / (DI/256)) & (NBATCH - 1);
    int c = blockIdx.x / ((DI/256) * NBATCH);
    int t0 = c * CLEN;

    float w[RNK];
    #pragma unroll
    for (int r = 0; r < RNK; r++) w[r] = dtw[e*RNK + r];
    float a[DS];
    #pragma unroll
    for (int n = 0; n < DS; n++) a[n] = -__expf(A_log[e*DS + n]);
    bool fast = true;
    #pragma unroll
    for (int n = 0; n < DS; n++)
        fast = fast && (fabsf(a[n] + (float)(n + 1)) <= 1e-4f * (float)(n + 1));
    float c0 = cw[e*4+0], c1 = cw[e*4+1], c2 = cw[e*4+2], c3 = cw[e*4+3];
    float cbe = cb[e], dtbe = dtb[e], dpe = Dp[e];

    size_t sidx = ((size_t)(b*DI) + e) * CHK + c;
    float hh[DS];
    if (PASS == 1) {
        #pragma unroll
        for (int n = 0; n < DS; n++) hh[n] = 0.f;
    } else {
        #pragma unroll
        for (int n = 0; n < DS; n++) hh[n] = hst[sidx*DS + n];
    }

    unsigned short* xrow = (unsigned short*)xy + ((size_t)(b*LSEQ) + t0) * xld + e;
    const unsigned short* drow = (const unsigned short*)(dbc + ((size_t)(b*LSEQ) + t0) * 80);

    unsigned short r0, r1, r2;
    if (PASS == 1) {
        if (c == 0) { r0 = 0; r1 = 0; r2 = 0; }
        else {
            r0 = xrow[-(ptrdiff_t)3*xld];
            r1 = xrow[-(ptrdiff_t)2*xld];
            r2 = xrow[-(ptrdiff_t)1*xld];
        }
        bound[sidx*4+0] = r0; bound[sidx*4+1] = r1; bound[sidx*4+2] = r2;
    } else {
        r0 = bound[sidx*4+0]; r1 = bound[sidx*4+1]; r2 = bound[sidx*4+2];
    }
    float p0 = u2f(r0), p1 = u2f(r1), p2 = u2f(r2);

    float S = 0.f;

#define SCAN_BODY(FAST_)                                                      \
    for (int t = 0; t < CLEN; t++) {                                          \
        float xt = u2f(xrow[(size_t)t * xld]);                                \
        float xv = silu_f(cbe + c0*p0 + c1*p1 + c2*p2 + c3*xt);               \
        p0 = p1; p1 = p2; p2 = xt;                                            \
        uint4 q[5];                                                           \
        const uint4* d4 = (const uint4*)(drow + (size_t)t * 80);              \
        _Pragma("unroll") for (int i = 0; i < 5; i++) q[i] = d4[i];           \
        uint4 q2[5];                                                          \
        _Pragma("unroll") for (int i = 0; i < 5; i++) q2[i] = d4[5 + i];      \
        const unsigned short* ds = (const unsigned short*)q;                  \
        const unsigned short* ds2 = (const unsigned short*)q2;                \
        float acc = dtbe;                                                     \
        _Pragma("unroll") for (int r = 0; r < RNK; r++) acc += w[r] * u2f(ds[r]); \
        float d = (acc > 20.f) ? acc : __logf(1.f + __expf(acc));             \
        float dx = d * xv;                                                    \
        if (FAST_) {                                                          \
            float rp = __expf(-d);                                            \
            float pw = rp;                                                    \
            _Pragma("unroll") for (int n = 0; n < DS; n++) {                  \
                hh[n] = pw * hh[n] + dx * u2f(ds[RNK + n]);                   \
                pw *= rp;                                                     \
            }                                                                 \
        } else {                                                              \
            _Pragma("unroll") for (int n = 0; n < DS; n++)                    \
                hh[n] = __expf(d * a[n]) * hh[n] + dx * u2f(ds[RNK + n]);     \
        }                                                                     \
        if (PASS == 1) {                                                      \
            S += d;                                                           \
        } else {                                                              \
            float y = xv * dpe;                                               \
            _Pragma("unroll") for (int n = 0; n < DS; n++) y += hh[n] * u2f(ds2[n]); \
            if (gate) {                                                       \
                float zt = u2f(xrow[(size_t)t * xld + 1536]);                 \
                y *= silu_f(zt);                                              \
            }                                                                 \
            bf16 yb = f2b(y);                                                 \
            xrow[(size_t)t * xld] = *(unsigned short*)&yb;                    \
        }                                                                     \
    }

    if (fast) { SCAN_BODY(1) } else { SCAN_BODY(0) }
#undef SCAN_BODY

    if (PASS == 1) {
        #pragma unroll
        for (int n = 0; n < DS; n++) hst[sidx*DS + n] = hh[n];
        Ssum[sidx] = S;
    }
}

// ---------------- combine chunk states ----------------
__global__ __launch_bounds__(256) void scan_combine_kernel(
    float* __restrict__ hst, const float* __restrict__ Ssum,
    const float* __restrict__ A_log)
{
    int tid = blockIdx.x * 256 + threadIdx.x;
    int n = tid & 15;
    int bee = tid >> 4;
    int e = bee % DI;
    float a = -__expf(A_log[e*DS + n]);
    float run = 0.f;
    for (int c = 0; c < CHK; c++) {
        size_t idx = ((size_t)bee * CHK + c) * DS + n;
        float tmp = hst[idx];
        hst[idx] = run;
        run = tmp + __expf(a * Ssum[(size_t)bee*CHK + c]) * run;
    }
}

// ---------------- pooled[b,d] = (1/L) sum_t h[b,t,d]*rs[b,t]*wf[d] ----------------
__global__ __launch_bounds__(128) void pool_kernel(
    const bf16* __restrict__ h, const float* __restrict__ rs,
    const float* __restrict__ wf, float* __restrict__ pooled)
{
    int b = blockIdx.x, dc = blockIdx.y, tc = blockIdx.z;
    int d = dc * 128 + threadIdx.x;
    float s = 0.f;
    int t0 = tc * 128;
    for (int t = t0; t < t0 + 128; t++) {
        int row = b * LSEQ + t;
        s += b2f(h[(size_t)row * DM + d]) * rs[row];
    }
    atomicAdd(&pooled[b * DM + d], s * wf[d] * (1.f / LSEQ));
}

// ---------------- classifier head + log_softmax + NLL ----------------
__global__ __launch_bounds__(128) void head_kernel(
    const float* __restrict__ pooled, const float* __restrict__ cls_w,
    const float* __restrict__ cls_b, const int* __restrict__ labels,
    float* __restrict__ out)
{
    __shared__ float lg[80];
    int tid = threadIdx.x;
    if (tid < 80) {
        int b = tid / 10, c = tid % 10;
        float s = cls_b[c];
        for (int d = 0; d < DM; d++) s += pooled[b * DM + d] * cls_w[c * DM + d];
        lg[tid] = s;
    }
    __syncthreads();
    if (tid == 0) {
        float loss = 0.f;
        for (int b = 0; b < NBATCH; b++) {
            float mx = -1e30f;
            for (int c = 0; c < 10; c++) mx = fmaxf(mx, lg[b*10+c]);
            float se = 0.f;
            for (int c = 0; c < 10; c++) se += expf(lg[b*10+c] - mx);
            float lse = mx + logf(se);
            loss -= (lg[b*10 + labels[b]] - lse);
            for (int c = 0; c < 10; c++) out[b*10+c] = lg[b*10+c];
        }
        out[80] = loss / NBATCH;
    }
}

extern "C" void kernel_launch(void* const* d_in, const int* in_sizes, int n_in,
                              void* d_out, int out_size, void* d_ws, size_t ws_size,
                              hipStream_t stream) {
    const float* x          = (const float*)d_in[0];
    const int*   labels     = (const int*)d_in[1];
    const float* in_proj_w  = (const float*)d_in[2];
    const float* conv_w     = (const float*)d_in[3];
    const float* conv_b     = (const float*)d_in[4];
    const float* x_proj_w   = (const float*)d_in[5];
    const float* dt_w       = (const float*)d_in[6];
    const float* dt_b       = (const float*)d_in[7];
    const float* A_log      = (const float*)d_in[8];
    const float* D_param    = (const float*)d_in[9];
    const float* out_proj_w = (const float*)d_in[10];
    const float* norm_w     = (const float*)d_in[11];
    const float* normf_w    = (const float*)d_in[12];
    const float* cls_w      = (const float*)d_in[13];
    const float* cls_b      = (const float*)d_in[14];
    float* out = (float*)d_out;

    // fused path needs xz = [xin | z] at 3072 cols (~181 MB total workspace);
    // fall back to the unfused flow (separate gate GEMM) if ws is smaller.
    const size_t fixed = (size_t)MTOK*DM*2*2                 // h, xn
                       + (size_t)MTOK*80*2 + (size_t)MTOK*80*4
                       + (size_t)NBATCH*DI*CHK*DS*4 + (size_t)NBATCH*DI*CHK*4
                       + (size_t)NBATCH*DI*CHK*4*2
                       + (size_t)MTOK*4 + (size_t)NBATCH*DM*4
                       + (size_t)2*DI*DM*2 + (size_t)80*DI*2 + (size_t)DM*DI*2;
    const int fused = (ws_size >= fixed + (size_t)MTOK * (2*DI) * 2 + 1024) ? 1 : 0;
    const int XLD = fused ? 2*DI : DI;

    char* p = (char*)d_ws;
    bf16* h   = (bf16*)p;                 p += (size_t)MTOK * DM * 2;
    bf16* xn  = (bf16*)p;                 p += (size_t)MTOK * DM * 2;
    bf16* xz  = (bf16*)p;                 p += (size_t)MTOK * XLD * 2;   // [xin | z] (fused) or xin->y
    bf16* dbc = (bf16*)p;                 p += (size_t)MTOK * 80 * 2;
    float* dbcf = (float*)p;              p += (size_t)MTOK * 80 * 4;
    float* hst = (float*)p;               p += (size_t)NBATCH*DI*CHK*DS*4;
    float* Ssum = (float*)p;              p += (size_t)NBATCH*DI*CHK*4;
    unsigned short* bound = (unsigned short*)p; p += (size_t)NBATCH*DI*CHK*4*2;
    float* rsb    = (float*)p;            p += (size_t)MTOK * 4;
    float* pooled = (float*)p;            p += NBATCH * DM * 4;
    short* inw_b = (short*)p;             p += (size_t)2*DI*DM * 2;
    short* xw_b  = (short*)p;             p += (size_t)80*DI * 2;
    short* ow_b  = (short*)p;             p += (size_t)DM*DI * 2;

    cvt_kernel<<<(MTOK * DM) / 1024, 256, 0, stream>>>(x, h, MTOK * DM);
    hipMemsetAsync(pooled, 0, NBATCH * DM * sizeof(float), stream);

    int scan_grid = (DI/256) * NBATCH * CHK;   // 768

    for (int l = 0; l < 4; l++) {
        const float* inw = in_proj_w + (size_t)l * 2 * DI * DM;
        const float* cwl = conv_w + (size_t)l * DI * 4;
        const float* cbl = conv_b + (size_t)l * DI;
        const float* xwl = x_proj_w + (size_t)l * (RNK + 2*DS) * DI;
        const float* dwl = dt_w + (size_t)l * DI * RNK;
        const float* dbl = dt_b + (size_t)l * DI;
        const float* All = A_log + (size_t)l * DI * DS;
        const float* Dpl = D_param + (size_t)l * DI;
        const float* owl = out_proj_w + (size_t)l * DM * DI;

        cvt_kernel<<<(2*DI*DM)/1024, 256, 0, stream>>>(inw, (bf16*)inw_b, 2*DI*DM);
        cvt_kernel<<<(80*DI)/1024, 256, 0, stream>>>(xwl, (bf16*)xw_b, 80*DI);
        cvt_kernel<<<(DM*DI)/1024, 256, 0, stream>>>(owl, (bf16*)ow_b, DM*DI);

        rmsnorm_kernel<<<MTOK/4, 256, 0, stream>>>(h, norm_w + (size_t)l * DM, xn, nullptr);

        hipMemsetAsync(dbcf, 0, (size_t)MTOK * 80 * sizeof(float), stream);

        if (fused) {
            // xz[:, :1536] = xin, xz[:, 1536:] = z  in ONE GEMM (N=3072)
            mgemm<0><<<dim3(2*DI/BN, MTOK/BM), 256, 0, stream>>>(
                (const short*)xn, DM, inw_b, DM, xz, XLD, MTOK, 2*DI, DM);
        } else {
            mgemm<0><<<dim3(DI/BN, MTOK/BM), 256, 0, stream>>>(
                (const short*)xn, DM, inw_b, DM, xz, XLD, MTOK, DI, DM);
        }

        // dbc partials = silu(conv(xin)) @ xw^T   (split-K, conv fused)
        mgemm_conv<<<dim3(1, MTOK/BM, KSPLIT), 256, 0, stream>>>(
            (const short*)xz, XLD, xw_b, DI, dbcf, 80, MTOK, 80, DI,
            cwl, cbl, (DI/BK)/KSPLIT);
        cvt_kernel<<<(MTOK*80)/1024, 256, 0, stream>>>(dbcf, dbc, MTOK*80);

        // chunked scan: pass1 -> combine -> pass2 (pass2 fuses y *= silu(z))
        scan_pass_kernel<1><<<scan_grid, 256, 0, stream>>>(
            xz, XLD, 0, dbc, All, Dpl, dwl, dbl, cwl, cbl, hst, Ssum, bound);
        scan_combine_kernel<<<(NBATCH*DI*DS)/256, 256, 0, stream>>>(hst, Ssum, All);
        scan_pass_kernel<2><<<scan_grid, 256, 0, stream>>>(
            xz, XLD, fused, dbc, All, Dpl, dwl, dbl, cwl, cbl, hst, Ssum, bound);

        if (!fused) {
            // gating: y *= silu(xn @ in_w[1536:3072]^T)
            mgemm<3><<<dim3(DI/BN, MTOK/BM), 256, 0, stream>>>(
                (const short*)xn, DM, inw_b + (size_t)DI*DM, DM, xz, XLD, MTOK, DI, DM);
        }

        // h += y @ out_w^T
        mgemm<2><<<dim3(DM/BN, MTOK/BM), 256, 0, stream>>>(
            (const short*)xz, XLD, ow_b, DI, h, DM, MTOK, DM, DI);
    }

    rmsnorm_kernel<<<MTOK/4, 256, 0, stream>>>(h, normf_w, nullptr, rsb);
    pool_kernel<<<dim3(NBATCH, DM/128, LSEQ/128), 128, 0, stream>>>(h, rsb, normf_w, pooled);
    head_kernel<<<1, 128, 0, stream>>>(pooled, cls_w, cls_b, labels, out);
}